// Round 1
// baseline (126.244 us; speedup 1.0000x reference)
//
#include <hip/hip_runtime.h>
#include <math.h>

namespace {
constexpr int RADIUS = 9;
constexpr float EPSV = 1e-5f;
constexpr int N_ = 2, C_ = 64, H_ = 128, W_ = 192;
constexpr int HW  = H_ * W_;        // 24576
constexpr int CHW = C_ * HW;
constexpr int NOFF = RADIUS * RADIUS;   // 81
constexpr int OUT1 = N_ * NOFF * HW;    // 3,981,312 (offset of out_diss)

constexpr int TH = 8, TW = 8;       // output tile
constexpr int MT = 16;              // map tile edge = TH + 8
constexpr int MW = 20;              // padded LDS row stride (20 mod 32 -> exact 2-way, free)
constexpr int CB = 8;               // channels per LDS chunk
constexpr int NTHREADS = TH * TW * RADIUS;  // 576
}

// ---------------------------------------------------------------------------
// Kernel 1: per-pixel channel L2 norms -> inverse scale factors
// ---------------------------------------------------------------------------
__global__ void norms_kernel(const float* __restrict__ img,
                             const float* __restrict__ mp,
                             float* __restrict__ invI,
                             float* __restrict__ invM) {
    int q = blockIdx.x * blockDim.x + threadIdx.x;   // [0, N_*HW)
    if (q >= N_ * HW) return;
    int n = q / HW;
    int rem = q - n * HW;
    const float* pi = img + (size_t)n * CHW + rem;
    const float* pm = mp  + (size_t)n * CHW + rem;
    float si = 0.f, sm = 0.f;
#pragma unroll 8
    for (int c = 0; c < C_; ++c) {
        float a = pi[c * HW];
        float b = pm[c * HW];
        si = fmaf(a, a, si);
        sm = fmaf(b, b, sm);
    }
    invI[q] = 1.f / (sqrtf(si) + EPSV);
    invM[q] = 1.f / (sqrtf(sm) + EPSV);
}

// ---------------------------------------------------------------------------
// Kernel 2: local correlation (81 shifts), both outputs
//   out_cos [n,81,h,w]  = 1 - <map_scaled(shift), img_scaled>
//   out_diss[n,81,h,w]  =     <map_orig(shift),   img_scaled>
//   shift (i,j): map coord = clamp(y+i-9, x+j-9)
// block: 576 threads = 64 pixels (8x8) x 9 offset-rows
// ---------------------------------------------------------------------------
__global__ __launch_bounds__(NTHREADS)
void corr_kernel(const float* __restrict__ img,
                 const float* __restrict__ mp,
                 const float* __restrict__ invI,
                 const float* __restrict__ invM,
                 float* __restrict__ out) {
    __shared__ float sImg[CB][TH * TW];
    __shared__ float sMapS[CB][MT * MW];
    __shared__ float sMapO[CB][MT * MW];
    __shared__ float sInvM[MT * MT];
    __shared__ float sInvI[TH * TW];

    const int n   = blockIdx.z;
    const int by0 = blockIdx.y * TH;
    const int bx0 = blockIdx.x * TW;
    const int tid = threadIdx.x;
    const int p    = tid & 63;      // pixel within tile
    const int iOff = tid >> 6;      // offset-row i, 0..8
    const int py = p >> 3, px = p & 7;

    // stage inverse-norm tiles (done once; covered by first barrier in loop)
    if (tid < MT * MT) {
        int row = tid >> 4, col = tid & 15;
        int gy = min(max(by0 - RADIUS + row, 0), H_ - 1);
        int gx = min(max(bx0 - RADIUS + col, 0), W_ - 1);
        sInvM[tid] = invM[n * HW + gy * W_ + gx];
    }
    if (tid >= 512) {  // 512..575 -> 64 threads
        int r = tid - 512;
        sInvI[r] = invI[n * HW + (by0 + (r >> 3)) * W_ + bx0 + (r & 7)];
    }

    float accC[RADIUS] = {0.f, 0.f, 0.f, 0.f, 0.f, 0.f, 0.f, 0.f, 0.f};
    float accD[RADIUS] = {0.f, 0.f, 0.f, 0.f, 0.f, 0.f, 0.f, 0.f, 0.f};

    const float* imgN = img + (size_t)n * CHW;
    const float* mapN = mp  + (size_t)n * CHW;

    for (int c0 = 0; c0 < C_; c0 += CB) {
        __syncthreads();   // LDS safe to overwrite; also fences inv tiles (1st iter)
        // ---- stage CB channels: img tile (64) + map region (256) each ----
        constexpr int ITEMS = CB * (TH * TW + MT * MT);   // 8*320 = 2560
        for (int idx = tid; idx < ITEMS; idx += NTHREADS) {
            int c = idx / 320;
            int r = idx - c * 320;
            if (r < TH * TW) {
                int gy = by0 + (r >> 3), gx = bx0 + (r & 7);
                sImg[c][r] = imgN[(size_t)(c0 + c) * HW + gy * W_ + gx] * sInvI[r];
            } else {
                int r2 = r - TH * TW;          // [0,256)
                int row = r2 >> 4, col = r2 & 15;
                int gy = min(max(by0 - RADIUS + row, 0), H_ - 1);
                int gx = min(max(bx0 - RADIUS + col, 0), W_ - 1);
                float v = mapN[(size_t)(c0 + c) * HW + gy * W_ + gx];
                sMapO[c][row * MW + col] = v;
                sMapS[c][row * MW + col] = v * sInvM[r2];
            }
        }
        __syncthreads();
        // ---- accumulate ----
#pragma unroll
        for (int c = 0; c < CB; ++c) {
            float a = sImg[c][p];
            const float* ms = &sMapS[c][(py + iOff) * MW + px];
            const float* mo = &sMapO[c][(py + iOff) * MW + px];
#pragma unroll
            for (int j = 0; j < RADIUS; ++j) {
                accC[j] = fmaf(ms[j], a, accC[j]);
                accD[j] = fmaf(mo[j], a, accD[j]);
            }
        }
    }

    // ---- epilogue ----
    const int y = by0 + py, x = bx0 + px;
    float* oc = out + (size_t)n * NOFF * HW + y * W_ + x;
    float* od = oc + OUT1;
#pragma unroll
    for (int j = 0; j < RADIUS; ++j) {
        int idx = iOff * RADIUS + j;
        oc[(size_t)idx * HW] = 1.f - accC[j];
        od[(size_t)idx * HW] = accD[j];
    }
}

extern "C" void kernel_launch(void* const* d_in, const int* in_sizes, int n_in,
                              void* d_out, int out_size, void* d_ws, size_t ws_size,
                              hipStream_t stream) {
    const float* img = (const float*)d_in[0];
    const float* mp  = (const float*)d_in[1];
    float* out  = (float*)d_out;
    float* invI = (float*)d_ws;               // N_*HW floats
    float* invM = invI + N_ * HW;             // N_*HW floats

    int npix = N_ * HW;
    norms_kernel<<<(npix + 255) / 256, 256, 0, stream>>>(img, mp, invI, invM);

    dim3 grid(W_ / TW, H_ / TH, N_);
    corr_kernel<<<grid, NTHREADS, 0, stream>>>(img, mp, invI, invM, out);
}

// Round 2
// 102.681 us; speedup vs baseline: 1.2295x; 1.2295x over previous
//
#include <hip/hip_runtime.h>
#include <math.h>

namespace {
constexpr int RADIUS = 9;
constexpr float EPSV = 1e-5f;
constexpr int N_ = 2, C_ = 64, H_ = 128, W_ = 192;
constexpr int HW  = H_ * W_;            // 24576
constexpr int CHW = C_ * HW;
constexpr int NOFF = RADIUS * RADIUS;   // 81
constexpr int OUT1 = N_ * NOFF * HW;    // offset of out_diss

// corr tiling: block = (8 rows x 64 cols) for ONE (n, i); thread = 4 px
constexpr int YB = 8;
constexpr int XB = 64;
constexpr int TQ = XB / 4;              // 16 x-chunks
constexpr int NT = YB * TQ;             // 128 threads (2 full waves)
constexpr int CB = 4;                   // channels per stage round
constexpr int MS = XB + 16;             // 80 staged map cols: x0-12 .. x0+67
constexpr int MCH = MS / 4;             // 20 float4 chunks per map row
constexpr int IS = XB + 4;              // 68: img LDS stride (pad -> odd chunk count)
}

// ---------------------------------------------------------------------------
// Kernel 1: per-pixel inverse channel L2 norms
// ---------------------------------------------------------------------------
__global__ void norms_kernel(const float* __restrict__ img,
                             const float* __restrict__ mp,
                             float* __restrict__ invI,
                             float* __restrict__ invM) {
    int q = blockIdx.x * blockDim.x + threadIdx.x;
    if (q >= N_ * HW) return;
    int n = q / HW;
    int rem = q - n * HW;
    const float* pi = img + (size_t)n * CHW + rem;
    const float* pm = mp  + (size_t)n * CHW + rem;
    float si = 0.f, sm = 0.f;
#pragma unroll 8
    for (int c = 0; c < C_; ++c) {
        float a = pi[c * HW];
        float b = pm[c * HW];
        si = fmaf(a, a, si);
        sm = fmaf(b, b, sm);
    }
    invI[q] = 1.f / (sqrtf(si) + EPSV);
    invM[q] = 1.f / (sqrtf(sm) + EPSV);
}

// ---------------------------------------------------------------------------
// Kernel 2: raw correlation dotRaw = sum_c map[c, clamp(p+o)] * img[c, p]
//   out_diss = invI[p] * dotRaw
//   out_cos  = 1 - invM[p'] * invI[p] * dotRaw
// block: fixed (n, i); 8 rows x 64 cols; thread owns 4 px, acc[4][9] over j
// ---------------------------------------------------------------------------
__global__ __launch_bounds__(NT, 4)
void corr_kernel(const float* __restrict__ img,
                 const float* __restrict__ mp,
                 const float* __restrict__ invIg,
                 const float* __restrict__ invMg,
                 float* __restrict__ out) {
    __shared__ float sMap[CB][YB][MS];
    __shared__ float sImg[CB][YB][IS];
    __shared__ float sInvM[YB][MS];

    const int bz   = blockIdx.z;            // n*9 + i
    const int n    = bz / RADIUS;
    const int iOff = bz - n * RADIUS;
    const int y0 = blockIdx.y * YB;
    const int x0 = blockIdx.x * XB;
    const int tid = threadIdx.x;
    const int ty = tid >> 4;                // 0..7
    const int t  = tid & 15;                // 0..15 (4-px chunk)

    const float* imgN = img + (size_t)n * CHW;
    const float* mapN = mp  + (size_t)n * CHW;
    const int ybase = y0 + iOff - RADIUS;   // map row r -> clamp(ybase + r)

    // ---- stage invM halo tile once (covered by first barrier in loop) ----
    for (int idx = tid; idx < YB * MCH; idx += NT) {
        int r  = idx / MCH;
        int ch = idx - r * MCH;
        int gy = min(max(ybase + r, 0), H_ - 1);
        int gxs = x0 - 12 + 4 * ch;
        const float* src = invMg + n * HW + gy * W_;
        float4 v;
        if (gxs >= 0 && gxs <= W_ - 4) {
            v = *(const float4*)(src + gxs);
        } else {
            v.x = src[min(max(gxs + 0, 0), W_ - 1)];
            v.y = src[min(max(gxs + 1, 0), W_ - 1)];
            v.z = src[min(max(gxs + 2, 0), W_ - 1)];
            v.w = src[min(max(gxs + 3, 0), W_ - 1)];
        }
        *(float4*)&sInvM[r][4 * ch] = v;
    }

    float acc[4][RADIUS];
#pragma unroll
    for (int px = 0; px < 4; ++px)
#pragma unroll
        for (int j = 0; j < RADIUS; ++j) acc[px][j] = 0.f;

    for (int c0 = 0; c0 < C_; c0 += CB) {
        __syncthreads();
        // ---- stage map: CB*8*20 = 640 items = exactly 5 rounds ----
#pragma unroll
        for (int it = 0; it < 5; ++it) {
            int idx = it * NT + tid;
            int c   = idx / (YB * MCH);
            int rem = idx - c * (YB * MCH);
            int r   = rem / MCH;
            int ch  = rem - r * MCH;
            int gy  = min(max(ybase + r, 0), H_ - 1);
            int gxs = x0 - 12 + 4 * ch;
            const float* src = mapN + (size_t)(c0 + c) * HW + gy * W_;
            float4 v;
            if (gxs >= 0 && gxs <= W_ - 4) {
                v = *(const float4*)(src + gxs);
            } else {
                v.x = src[min(max(gxs + 0, 0), W_ - 1)];
                v.y = src[min(max(gxs + 1, 0), W_ - 1)];
                v.z = src[min(max(gxs + 2, 0), W_ - 1)];
                v.w = src[min(max(gxs + 3, 0), W_ - 1)];
            }
            *(float4*)&sMap[c][r][4 * ch] = v;
        }
        // ---- stage img: CB*8*16 = 512 items = exactly 4 rounds, interior ----
#pragma unroll
        for (int it = 0; it < 4; ++it) {
            int idx = it * NT + tid;
            int c   = idx >> 7;
            int rem = idx & 127;
            int r   = rem >> 4;
            int ch  = rem & 15;
            float4 v = *(const float4*)(imgN + (size_t)(c0 + c) * HW +
                                        (size_t)(y0 + r) * W_ + x0 + 4 * ch);
            *(float4*)&sImg[c][r][4 * ch] = v;
        }
        __syncthreads();
        // ---- accumulate: per ch, 5 ds_read_b128 + 36 FMAs ----
#pragma unroll
        for (int c = 0; c < CB; ++c) {
            float4 a4 = *(const float4*)&sImg[c][ty][4 * t];
            float w[16];
            *(float4*)&w[0]  = *(const float4*)&sMap[c][ty][4 * t + 0];
            *(float4*)&w[4]  = *(const float4*)&sMap[c][ty][4 * t + 4];
            *(float4*)&w[8]  = *(const float4*)&sMap[c][ty][4 * t + 8];
            *(float4*)&w[12] = *(const float4*)&sMap[c][ty][4 * t + 12];
            float a[4] = {a4.x, a4.y, a4.z, a4.w};
#pragma unroll
            for (int px = 0; px < 4; ++px)
#pragma unroll
                for (int j = 0; j < RADIUS; ++j)
                    acc[px][j] = fmaf(w[px + j + 3], a[px], acc[px][j]);
        }
    }

    // ---- epilogue: scale by invI (pixel) and invM (shifted pixel) ----
    const int y  = y0 + ty;
    const int xb = x0 + 4 * t;
    float4 vI = *(const float4*)(invIg + n * HW + y * W_ + xb);
    float wI[4] = {vI.x, vI.y, vI.z, vI.w};
    float wm[16];
    *(float4*)&wm[0]  = *(const float4*)&sInvM[ty][4 * t + 0];
    *(float4*)&wm[4]  = *(const float4*)&sInvM[ty][4 * t + 4];
    *(float4*)&wm[8]  = *(const float4*)&sInvM[ty][4 * t + 8];
    *(float4*)&wm[12] = *(const float4*)&sInvM[ty][4 * t + 12];

    float* ocB = out + (size_t)n * NOFF * HW + (size_t)y * W_ + xb;
#pragma unroll
    for (int j = 0; j < RADIUS; ++j) {
        int o = iOff * RADIUS + j;
        float4 vd, vc;
        vd.x = acc[0][j] * wI[0];
        vd.y = acc[1][j] * wI[1];
        vd.z = acc[2][j] * wI[2];
        vd.w = acc[3][j] * wI[3];
        vc.x = 1.f - vd.x * wm[0 + j + 3];
        vc.y = 1.f - vd.y * wm[1 + j + 3];
        vc.z = 1.f - vd.z * wm[2 + j + 3];
        vc.w = 1.f - vd.w * wm[3 + j + 3];
        *(float4*)(ocB + (size_t)o * HW) = vc;
        *(float4*)(ocB + OUT1 + (size_t)o * HW) = vd;
    }
}

extern "C" void kernel_launch(void* const* d_in, const int* in_sizes, int n_in,
                              void* d_out, int out_size, void* d_ws, size_t ws_size,
                              hipStream_t stream) {
    const float* img = (const float*)d_in[0];
    const float* mp  = (const float*)d_in[1];
    float* out  = (float*)d_out;
    float* invI = (float*)d_ws;
    float* invM = invI + N_ * HW;

    int npix = N_ * HW;
    norms_kernel<<<(npix + 255) / 256, 256, 0, stream>>>(img, mp, invI, invM);

    dim3 grid(W_ / XB, H_ / YB, N_ * RADIUS);   // 3 x 16 x 18 = 864 blocks
    corr_kernel<<<grid, NT, 0, stream>>>(img, mp, invI, invM, out);
}